// Round 5
// baseline (282.974 us; speedup 1.0000x reference)
//
#include <hip/hip_runtime.h>
#include <hip/hip_cooperative_groups.h>
#include <math.h>

namespace cg = cooperative_groups;

// Static problem config
#define NB     16      // graphs
#define NN     64      // nodes per graph
#define KK     4       // subgraph size
#define PP     6       // (K-1)!
#define HH     64      // hid dim
#define NSUB   2048    // total subgraphs
#define NC0    65      // c0 in [0,64]
#define NMASK  16      // 2^K
#define NCOMBO (NC0*NMASK)
#define NVAR   5       // var = 0 (not in subg) or 1+j (i == subgs[j])
#define GRID_F 512     // fused-kernel grid (2 blocks/CU needed; 4/CU capacity)

// Workspace layout (float element offsets)
#define OFF_ROWSUM 0                 // 16*64             = 1024
#define OFF_LABW   1024              // 4*6*64            = 1536
#define OFF_W1SUM  2560              // 64
#define OFF_BASEW  2624              // 5*64              = 320
#define OFF_T2     2944              // 5*1040*64         = 332800
#define OFF_GKEYS  335744            // 16*64 (as uint)   = 1024

// allperm rows: ap[j][p] for j in 0..3, p in 0..5
__device__ __constant__ int d_ap[4][6] = {
    {0,0,0,0,0,0},{1,1,2,2,3,3},{2,3,1,3,1,2},{3,2,3,1,2,1}};

static __device__ inline float selu_f(float x) {
    const float alpha = 1.6732632423543772f;
    const float scale = 1.0507009873554805f;
    return x > 0.0f ? scale * x : scale * alpha * expm1f(x);
}
// order-preserving float->uint encoding for atomicMax-based segment max
static __device__ inline unsigned enc_f(float x) {
    unsigned b = __float_as_uint(x);
    return (b & 0x80000000u) ? ~b : (b | 0x80000000u);
}
static __device__ inline float dec_f(unsigned k) {
    unsigned b = (k & 0x80000000u) ? (k & 0x7FFFFFFFu) : ~k;
    return __uint_as_float(b);
}

// ================= Fused cooperative kernel: prep -> table -> main ============
// 512 blocks x 256 threads; launch_bounds(256,4) => 4 blocks/CU capacity,
// we need only 2/CU -> cooperative launch has 2x occupancy margin.
__global__ __launch_bounds__(256, 4) void k_fused(
    const float* __restrict__ adj, const int* __restrict__ subgs,
    const float* __restrict__ idemb, const float* __restrict__ id_w,
    const float* __restrict__ id_b, const float* __restrict__ set1_w,
    const float* __restrict__ set1_b, const float* __restrict__ set2_w,
    const float* __restrict__ set2_b, float* __restrict__ ws)
{
    cg::grid_group grid = cg::this_grid();
    const int g   = blockIdx.x;
    const int tid = threadIdx.x;
    const int w   = tid >> 6, h = tid & 63;
    __shared__ int   sub[KK];
    __shared__ float gpart[4][HH];

    // ---------------- Phase 1: prep (blocks 0..46 active) ----------------
    if (g < NB) {                                   // rowsums, graph g
        if (tid < 64) {
            const float4* row = reinterpret_cast<const float4*>(adj + (g*NN + tid)*NN);
            float s = 0.f;
            #pragma unroll
            for (int k = 0; k < 16; ++k) { float4 v = row[k]; s += v.x + v.y + v.z + v.w; }
            ws[OFF_ROWSUM + g*NN + tid] = s;
        }
    } else if (g < NB + KK*PP) {                    // labW, one (j,p) per block
        if (tid < 64) {
            const int jp = g - NB;                  // 0..23
            const int j = jp / PP, p = jp % PP;
            const float sc = (float)(j+1) * 1000.0f;
            const float* er = idemb + d_ap[j][p]*HH;
            float s = 0.f;
            #pragma unroll
            for (int hh = 0; hh < HH; ++hh) s += (er[hh] * sc) * id_w[hh*HH + tid];
            ws[OFF_LABW + jp*HH + tid] = s;
        }
    } else if (g == NB + KK*PP) {                   // w1sum (block 40)
        if (tid < 64) {
            float s = 0.f;
            for (int hh = 0; hh < HH; ++hh) s += id_w[hh*HH + tid];
            ws[OFF_W1SUM + tid] = s;
        }
    } else if (g < NB + KK*PP + 1 + NVAR) {         // baseW, blocks 41..45
        if (tid < 64) {
            const int var = g - (NB + KK*PP + 1);   // 0..4
            if (var == 0) {
                float cs = 0.f;
                for (int hp = 0; hp < HH; ++hp) cs += set1_w[hp*HH + tid];
                ws[OFF_BASEW + tid] = 6.0f * cs + set1_b[tid];
            } else {
                const int j = var - 1;
                const float sc = (float)(j+1) * 1000.0f;
                float l = 0.f;
                #pragma unroll
                for (int p = 0; p < PP; ++p) l += idemb[d_ap[j][p]*HH + tid];
                l *= sc;                            // lsum[j][tid]
                float d = 0.f;
                #pragma unroll
                for (int hp = 0; hp < HH; ++hp) d += __shfl(l, hp, 64) * set1_w[hp*HH + tid];
                ws[OFF_BASEW + var*HH + tid] = d + set1_b[tid];
            }
        }
    } else if (g == NB + KK*PP + 1 + NVAR) {        // gk init (block 46)
        if (tid < 64) {
            unsigned* gk = reinterpret_cast<unsigned*>(ws) + OFF_GKEYS;
            for (int i = tid; i < NB*HH; i += 64) gk[i] = 0u;
        }
    }
    grid.sync();

    // ---------------- Phase 2: T2 table (1040 combos over 260 blocks x 4 waves)
    if (g < NCOMBO/4) {
        const int c = g*4 + w;                      // combo id, wave-private
        const int c0 = c >> 4, mask = c & 15;
        const float* labW  = ws + OFF_LABW;
        const float* w1sum = ws + OFF_W1SUM;
        const float* baseW = ws + OFF_BASEW;
        const float fc0 = (float)c0;
        float acc = 0.f;
        #pragma unroll
        for (int p = 0; p < PP; ++p) {
            float arg = fc0 * w1sum[h] + id_b[h];
            #pragma unroll
            for (int j = 0; j < KK; ++j)
                if ((mask >> j) & 1) arg += labW[(j*PP + p)*HH + h];
            acc += selu_f(arg);
        }
        float o = 0.f;
        #pragma unroll
        for (int hp = 0; hp < HH; ++hp) o += __shfl(acc, hp, 64) * set1_w[hp*HH + h];
        #pragma unroll
        for (int var = 0; var < NVAR; ++var)
            ws[OFF_T2 + (var*NCOMBO + c)*HH + h] = selu_f(o + baseW[var*HH + h]);
    }
    grid.sync();

    // ---------------- Phase 3: main pass, 4 subgraphs per block ----------------
    const float* T2 = ws + OFF_T2;
    #pragma unroll
    for (int ss = 0; ss < NSUB/GRID_F; ++ss) {
        const int s = g + ss*GRID_F;
        const int b = s >> 7;                       // 128 subgraphs per graph
        if (tid < KK) sub[tid] = subgs[s*KK + tid];
        __syncthreads();
        const int s0 = sub[0], s1 = sub[1], s2 = sub[2], s3 = sub[3];
        const float* adjb = adj + b*NN*NN;
        const float* rs   = ws + OFF_ROWSUM + b*NN;
        float facc = 0.f;
        #pragma unroll 4
        for (int it = 0; it < 16; ++it) {
            const int i = w*16 + it;
            const float* arow = adjb + i*NN;
            const float a0 = arow[s0], a1 = arow[s1], a2 = arow[s2], a3 = arow[s3];
            const float c0f = rs[i] - (a0 + a1 + a2 + a3);
            const int ic0 = (int)(c0f + 0.5f);      // exact small integer
            const int mask = (a0 != 0.f ? 1 : 0) | (a1 != 0.f ? 2 : 0)
                           | (a2 != 0.f ? 4 : 0) | (a3 != 0.f ? 8 : 0);
            const int var = (i==s0) ? 1 : (i==s1) ? 2 : (i==s2) ? 3 : (i==s3) ? 4 : 0;
            facc += T2[(var*NCOMBO + ic0*NMASK + mask)*HH + h];
        }
        gpart[w][h] = facc;
        __syncthreads();
        if (w == 0) {
            const float gsum = gpart[0][h] + gpart[1][h] + gpart[2][h] + gpart[3][h];
            float o = set2_b[h];
            #pragma unroll
            for (int hp = 0; hp < HH; ++hp)
                o += __shfl(gsum, hp, 64) * set2_w[hp*HH + h];
            const float gq = selu_f(o);
            unsigned* gk = reinterpret_cast<unsigned*>(ws) + OFF_GKEYS;
            atomicMax(gk + b*HH + h, enc_f(gq));
        }
        __syncthreads();                            // before sub[]/gpart reuse
    }
}

// ================= Fallback path (proven bit-exact in R3) =====================
__global__ __launch_bounds__(64) void k_prep(
    const float* __restrict__ adj, const float* __restrict__ idemb,
    const float* __restrict__ id_w, const float* __restrict__ set1_w,
    const float* __restrict__ set1_b, float* __restrict__ ws)
{
    const int t = threadIdx.x;
    const int blk = blockIdx.x;
    if (blk < NB) {
        const float4* row = reinterpret_cast<const float4*>(adj + (blk*NN + t)*NN);
        float s = 0.f;
        #pragma unroll
        for (int k = 0; k < 16; ++k) { float4 v = row[k]; s += v.x + v.y + v.z + v.w; }
        ws[OFF_ROWSUM + blk*NN + t] = s;
        return;
    }
    if (blk > NB) {
        const int jp = blk - NB - 1;
        const int j = jp / PP, p = jp % PP;
        const float sc = (float)(j+1) * 1000.0f;
        const float* er = idemb + d_ap[j][p]*HH;
        float s = 0.f;
        #pragma unroll
        for (int h = 0; h < HH; ++h) s += (er[h] * sc) * id_w[h*HH + t];
        ws[OFF_LABW + jp*HH + t] = s;
        return;
    }
    float* w1sum = ws + OFF_W1SUM;
    float* baseW = ws + OFF_BASEW;
    unsigned* gk = reinterpret_cast<unsigned*>(ws) + OFF_GKEYS;
    {
        float s = 0.f;
        for (int h = 0; h < HH; ++h) s += id_w[h*HH + t];
        w1sum[t] = s;
    }
    __shared__ float lsum[KK][HH];
    for (int j = 0; j < KK; ++j) {
        const float sc = (float)(j+1) * 1000.0f;
        float s = 0.f;
        for (int p = 0; p < PP; ++p) s += idemb[d_ap[j][p]*HH + t];
        lsum[j][t] = s * sc;
    }
    __syncthreads();
    {
        float cs = 0.f;
        for (int hp = 0; hp < HH; ++hp) cs += set1_w[hp*HH + t];
        baseW[t] = 6.0f * cs + set1_b[t];
        for (int j = 0; j < KK; ++j) {
            float d = 0.f;
            for (int hp = 0; hp < HH; ++hp) d += lsum[j][hp] * set1_w[hp*HH + t];
            baseW[(1+j)*HH + t] = d + set1_b[t];
        }
    }
    for (int i = t; i < NB*HH; i += 64) gk[i] = 0u;
}

__global__ __launch_bounds__(64) void k_table(
    const float* __restrict__ id_b, const float* __restrict__ set1_w,
    float* __restrict__ ws)
{
    const int c0   = blockIdx.x >> 4;
    const int mask = blockIdx.x & 15;
    const int t = threadIdx.x;
    const float* labW  = ws + OFF_LABW;
    const float* w1sum = ws + OFF_W1SUM;
    const float* baseW = ws + OFF_BASEW;
    const float fc0 = (float)c0;
    float acc = 0.f;
    #pragma unroll
    for (int p = 0; p < PP; ++p) {
        float arg = fc0 * w1sum[t] + id_b[t];
        #pragma unroll
        for (int j = 0; j < KK; ++j)
            if ((mask >> j) & 1) arg += labW[(j*PP + p)*HH + t];
        acc += selu_f(arg);
    }
    __shared__ float S[HH];
    S[t] = acc;
    __syncthreads();
    float o = 0.f;
    #pragma unroll
    for (int hp = 0; hp < HH; ++hp) o += S[hp] * set1_w[hp*HH + t];
    #pragma unroll
    for (int var = 0; var < NVAR; ++var)
        ws[OFF_T2 + (var*NCOMBO + blockIdx.x)*HH + t] = selu_f(o + baseW[var*HH + t]);
}

__global__ __launch_bounds__(256) void k_main(
    const float* __restrict__ adj, const int* __restrict__ subgs,
    const float* __restrict__ set2_w, const float* __restrict__ set2_b,
    float* __restrict__ ws)
{
    const int s = blockIdx.x;
    const int b = s >> 7;
    __shared__ int sub[KK];
    __shared__ float gpart[4][HH];
    if (threadIdx.x < KK) sub[threadIdx.x] = subgs[s*KK + threadIdx.x];
    __syncthreads();
    const int w = threadIdx.x >> 6, h = threadIdx.x & 63;
    const int s0 = sub[0], s1 = sub[1], s2 = sub[2], s3 = sub[3];
    const float* adjb = adj + b*NN*NN;
    const float* rs   = ws + OFF_ROWSUM + b*NN;
    const float* T2   = ws + OFF_T2;
    float facc = 0.f;
    #pragma unroll 4
    for (int it = 0; it < 16; ++it) {
        const int i = w*16 + it;
        const float* arow = adjb + i*NN;
        const float a0 = arow[s0], a1 = arow[s1], a2 = arow[s2], a3 = arow[s3];
        const float c0f = rs[i] - (a0 + a1 + a2 + a3);
        const int ic0 = (int)(c0f + 0.5f);
        const int mask = (a0 != 0.f ? 1 : 0) | (a1 != 0.f ? 2 : 0)
                       | (a2 != 0.f ? 4 : 0) | (a3 != 0.f ? 8 : 0);
        const int var = (i==s0) ? 1 : (i==s1) ? 2 : (i==s2) ? 3 : (i==s3) ? 4 : 0;
        facc += T2[(var*NCOMBO + ic0*NMASK + mask)*HH + h];
    }
    gpart[w][h] = facc;
    __syncthreads();
    if (w == 0) gpart[0][h] = gpart[0][h] + gpart[1][h] + gpart[2][h] + gpart[3][h];
    __syncthreads();
    if (w == 0) {
        float o = set2_b[h];
        #pragma unroll
        for (int hp = 0; hp < HH; ++hp)
            o += gpart[0][hp] * set2_w[hp*HH + h];
        const float gq = selu_f(o);
        unsigned* gk = reinterpret_cast<unsigned*>(ws) + OFF_GKEYS;
        atomicMax(gk + b*HH + h, enc_f(gq));
    }
}

// ---------------- Kernel D: head — one block (CU) per graph row ----------------
__global__ __launch_bounds__(256) void k_head(
    const float* __restrict__ reg_w1, const float* __restrict__ reg_b1,
    const float* __restrict__ reg_w2, const float* __restrict__ reg_b2,
    const float* __restrict__ reg_ln_g, const float* __restrict__ reg_ln_b,
    const float* __restrict__ out_w, const float* __restrict__ out_b,
    const float* __restrict__ ws, float* __restrict__ out)
{
    __shared__ float swgt[2*KK*HH*HH];
    __shared__ float gs[HH];
    const int tid = threadIdx.x;
    {
        const float4* g1 = reinterpret_cast<const float4*>(reg_w1);
        const float4* g2 = reinterpret_cast<const float4*>(reg_w2);
        float4* s4 = reinterpret_cast<float4*>(swgt);
        #pragma unroll
        for (int i = 0; i < 16; ++i) s4[i*256 + tid] = g1[i*256 + tid];
        #pragma unroll
        for (int i = 0; i < 16; ++i) s4[4096 + i*256 + tid] = g2[i*256 + tid];
    }
    __syncthreads();
    if (tid >= 64) return;
    const int r = blockIdx.x;
    const int h = tid;
    const unsigned* gk = reinterpret_cast<const unsigned*>(ws) + OFF_GKEYS;
    float g = dec_f(gk[r*HH + h]);
    for (int blk = 0; blk < 4; ++blk) {
        const float* w1 = swgt + blk*HH*HH;
        const float* w2 = swgt + KK*HH*HH + blk*HH*HH;
        gs[h] = g;
        __syncthreads();
        float t1 = reg_b1[blk*HH + h];
        #pragma unroll
        for (int hp = 0; hp < HH; ++hp) t1 += gs[hp] * w1[hp*HH + h];
        t1 = fmaxf(t1, 0.f);
        gs[h] = t1;
        __syncthreads();
        float u = reg_b2[blk*HH + h];
        #pragma unroll
        for (int hp = 0; hp < HH; ++hp) u += gs[hp] * w2[hp*HH + h];
        __syncthreads();
        float m = u;
        #pragma unroll
        for (int d = 1; d < 64; d <<= 1) m += __shfl_xor(m, d, 64);
        m *= (1.0f/64.0f);
        const float dv = u - m;
        float v = dv * dv;
        #pragma unroll
        for (int d = 1; d < 64; d <<= 1) v += __shfl_xor(v, d, 64);
        v *= (1.0f/64.0f);
        const float y = dv / sqrtf(v + 1e-5f) * reg_ln_g[blk*HH + h] + reg_ln_b[blk*HH + h];
        g += fmaxf(y, 0.f);
    }
    float pr = g * out_w[h];
    #pragma unroll
    for (int d = 1; d < 64; d <<= 1) pr += __shfl_xor(pr, d, 64);
    if (h == 0) out[r] = pr + out_b[0];
}

extern "C" void kernel_launch(void* const* d_in, const int* in_sizes, int n_in,
                              void* d_out, int out_size, void* d_ws, size_t ws_size,
                              hipStream_t stream)
{
    const float* adj     = (const float*)d_in[1];
    const int*   subgs   = (const int*)  d_in[2];
    const float* idemb   = (const float*)d_in[10];
    const float* id_w    = (const float*)d_in[11];
    const float* id_b    = (const float*)d_in[12];
    const float* set1_w  = (const float*)d_in[13];
    const float* set1_b  = (const float*)d_in[14];
    const float* set2_w  = (const float*)d_in[15];
    const float* set2_b  = (const float*)d_in[16];
    const float* reg_w1  = (const float*)d_in[17];
    const float* reg_b1  = (const float*)d_in[18];
    const float* reg_w2  = (const float*)d_in[19];
    const float* reg_b2  = (const float*)d_in[20];
    const float* reg_lng = (const float*)d_in[21];
    const float* reg_lnb = (const float*)d_in[22];
    const float* out_w   = (const float*)d_in[23];
    const float* out_b   = (const float*)d_in[24];
    float* ws  = (float*)d_ws;
    float* out = (float*)d_out;

    void* args[] = { (void*)&adj, (void*)&subgs, (void*)&idemb, (void*)&id_w,
                     (void*)&id_b, (void*)&set1_w, (void*)&set1_b,
                     (void*)&set2_w, (void*)&set2_b, (void*)&ws };
    hipError_t ce = hipLaunchCooperativeKernel((void*)k_fused, dim3(GRID_F),
                                               dim3(256), args, 0, stream);
    if (ce != hipSuccess) {
        // Deterministic fallback: proven 3-kernel path (bit-exact, R3)
        hipLaunchKernelGGL(k_prep,  dim3(NB + 1 + KK*PP), dim3(64), 0, stream,
                           adj, idemb, id_w, set1_w, set1_b, ws);
        hipLaunchKernelGGL(k_table, dim3(NCOMBO), dim3(64),  0, stream,
                           id_b, set1_w, ws);
        hipLaunchKernelGGL(k_main,  dim3(NSUB),   dim3(256), 0, stream,
                           adj, subgs, set2_w, set2_b, ws);
    }
    hipLaunchKernelGGL(k_head, dim3(NB), dim3(256), 0, stream,
                       reg_w1, reg_b1, reg_w2, reg_b2, reg_lng, reg_lnb,
                       out_w, out_b, ws, out);
}

// Round 6
// 190.018 us; speedup vs baseline: 1.4892x; 1.4892x over previous
//
#include <hip/hip_runtime.h>
#include <math.h>

// Static problem config
#define NB     16      // graphs
#define NN     64      // nodes per graph
#define KK     4       // subgraph size
#define PP     6       // (K-1)!
#define HH     64      // hid dim
#define NSUB   2048    // total subgraphs
#define NC0    65      // c0 in [0,64]
#define NMASK  16      // 2^K
#define NCOMBO (NC0*NMASK)
#define NVAR   5       // var = 0 (not in subg) or 1+j (i == subgs[j])

// Workspace layout (float element offsets)
#define OFF_T2     0                 // 5*1040*64         = 332800
#define OFF_GKEYS  332800            // 16*64 (as uint)   = 1024

// allperm rows: ap[j][p] for j in 0..3, p in 0..5
__device__ __constant__ int d_ap[4][6] = {
    {0,0,0,0,0,0},{1,1,2,2,3,3},{2,3,1,3,1,2},{3,2,3,1,2,1}};

static __device__ inline float selu_f(float x) {
    const float alpha = 1.6732632423543772f;
    const float scale = 1.0507009873554805f;
    return x > 0.0f ? scale * x : scale * alpha * expm1f(x);
}
// order-preserving float->uint encoding for atomicMax-based segment max
static __device__ inline unsigned enc_f(float x) {
    unsigned b = __float_as_uint(x);
    return (b & 0x80000000u) ? ~b : (b | 0x80000000u);
}
static __device__ inline float dec_f(unsigned k) {
    unsigned b = (k & 0x80000000u) ? (k & 0x7FFFFFFFu) : ~k;
    return __uint_as_float(b);
}

// ======= Kernel 1: T2 table, fully self-contained (prep folded in) =========
// One block per (c0,mask) combo; every thread recomputes the tiny prep
// values (w1sum, labW, baseW) in-register — redundancy is cheaper than a
// separate kernel launch + dependency gap. FP summation orders identical
// to the verified R3/R5 paths (ascending loops; __shfl broadcast dots).
__global__ __launch_bounds__(64) void k_tableX(
    const float* __restrict__ idemb, const float* __restrict__ id_w,
    const float* __restrict__ id_b, const float* __restrict__ set1_w,
    const float* __restrict__ set1_b, float* __restrict__ ws)
{
    const int c = blockIdx.x;              // combo id
    const int c0 = c >> 4, mask = c & 15;
    const int t = threadIdx.x;             // 0..63 = output channel

    if (c == 0) {                          // gk init (done before k_main runs)
        unsigned* gk = reinterpret_cast<unsigned*>(ws) + OFF_GKEYS;
        for (int i = t; i < NB*HH; i += 64) gk[i] = 0u;
    }

    // w1sum[t] = sum_h id_w[h][t]  (ones-row through id_w), ascending h
    float w1s = 0.f;
    for (int hh = 0; hh < HH; ++hh) w1s += id_w[hh*HH + t];

    // labW[j][p] scalars for j in mask (ascending-h dot, same as R3 k_prep)
    float labw[KK][PP];
    #pragma unroll
    for (int j = 0; j < KK; ++j) {
        if ((mask >> j) & 1) {
            const float sc = (float)(j+1) * 1000.0f;
            #pragma unroll
            for (int p = 0; p < PP; ++p) {
                const float* er = idemb + d_ap[j][p]*HH;
                float s = 0.f;
                for (int hh = 0; hh < HH; ++hh) s += (er[hh] * sc) * id_w[hh*HH + t];
                labw[j][p] = s;
            }
        }
    }

    // acc = sum_p selu(c0*w1sum + id_b + sum_{j in mask} labW[j][p])
    const float fc0 = (float)c0;
    float acc = 0.f;
    #pragma unroll
    for (int p = 0; p < PP; ++p) {
        float arg = fc0 * w1s + id_b[t];
        #pragma unroll
        for (int j = 0; j < KK; ++j)
            if ((mask >> j) & 1) arg += labw[j][p];
        acc += selu_f(arg);
    }

    // SW[t] = acc-row @ set1_w  (ascending hp, __shfl broadcast — verified R5)
    float o = 0.f;
    #pragma unroll
    for (int hp = 0; hp < HH; ++hp) o += __shfl(acc, hp, 64) * set1_w[hp*HH + t];

    // baseW[var][t], var 0..4 (orders identical to R3 k_prep / R5 phase 1)
    float bw[NVAR];
    {
        float cs = 0.f;
        for (int hp = 0; hp < HH; ++hp) cs += set1_w[hp*HH + t];
        bw[0] = 6.0f * cs + set1_b[t];
    }
    #pragma unroll
    for (int j = 0; j < KK; ++j) {
        const float sc = (float)(j+1) * 1000.0f;
        float l = 0.f;
        #pragma unroll
        for (int p = 0; p < PP; ++p) l += idemb[d_ap[j][p]*HH + t];
        l *= sc;                           // lsum[j][t]
        float d = 0.f;
        #pragma unroll
        for (int hp = 0; hp < HH; ++hp) d += __shfl(l, hp, 64) * set1_w[hp*HH + t];
        bw[1+j] = d + set1_b[t];
    }

    #pragma unroll
    for (int var = 0; var < NVAR; ++var)
        ws[OFF_T2 + (var*NCOMBO + c)*HH + t] = selu_f(o + bw[var]);
}

// ======= Kernel 2: main pass — 2 subgraphs (same graph) per block ==========
// Blocks stage their graph's 64 adj rowsums in LDS (same float4 order as the
// old k_prep → bit-identical), then do the T2 gather + set2 matvec + atomic.
__global__ __launch_bounds__(256) void k_main(
    const float* __restrict__ adj, const int* __restrict__ subgs,
    const float* __restrict__ set2_w, const float* __restrict__ set2_b,
    float* __restrict__ ws)
{
    const int g = blockIdx.x;             // 0..1023; 64 blocks per graph
    const int b = g >> 6;                 // graph id (2g and 2g+1 share it)
    const int tid = threadIdx.x;
    const int w = tid >> 6, h = tid & 63;
    __shared__ float rs_s[NN];
    __shared__ int   sub[KK];
    __shared__ float gpart[4][HH];

    if (tid < 64) {                        // rowsum of row tid, graph b
        const float4* row = reinterpret_cast<const float4*>(adj + (b*NN + tid)*NN);
        float s = 0.f;
        #pragma unroll
        for (int k = 0; k < 16; ++k) { float4 v = row[k]; s += v.x + v.y + v.z + v.w; }
        rs_s[tid] = s;
    }
    const float* adjb = adj + b*NN*NN;
    const float* T2   = ws + OFF_T2;
    unsigned* gk = reinterpret_cast<unsigned*>(ws) + OFF_GKEYS;

    #pragma unroll
    for (int ss = 0; ss < 2; ++ss) {
        const int s = g*2 + ss;
        if (tid < KK) sub[tid] = subgs[s*KK + tid];
        __syncthreads();                   // covers rs_s (ss=0) and sub[]
        const int s0 = sub[0], s1 = sub[1], s2 = sub[2], s3 = sub[3];
        float facc = 0.f;
        #pragma unroll 4
        for (int it = 0; it < 16; ++it) {
            const int i = w*16 + it;
            const float* arow = adjb + i*NN;
            const float a0 = arow[s0], a1 = arow[s1], a2 = arow[s2], a3 = arow[s3];
            const float c0f = rs_s[i] - (a0 + a1 + a2 + a3);
            const int ic0 = (int)(c0f + 0.5f);   // exact small integer
            const int mask = (a0 != 0.f ? 1 : 0) | (a1 != 0.f ? 2 : 0)
                           | (a2 != 0.f ? 4 : 0) | (a3 != 0.f ? 8 : 0);
            const int var = (i==s0) ? 1 : (i==s1) ? 2 : (i==s2) ? 3 : (i==s3) ? 4 : 0;
            facc += T2[(var*NCOMBO + ic0*NMASK + mask)*HH + h];
        }
        gpart[w][h] = facc;
        __syncthreads();
        if (w == 0) {
            const float gsum = gpart[0][h] + gpart[1][h] + gpart[2][h] + gpart[3][h];
            float o = set2_b[h];
            #pragma unroll
            for (int hp = 0; hp < HH; ++hp)
                o += __shfl(gsum, hp, 64) * set2_w[hp*HH + h];
            const float gq = selu_f(o);
            atomicMax(gk + b*HH + h, enc_f(gq));
        }
        __syncthreads();                   // before sub[]/gpart reuse
    }
}

// ======= Kernel 3: head — one block (CU) per graph row (verified R2+) ======
__global__ __launch_bounds__(256) void k_head(
    const float* __restrict__ reg_w1, const float* __restrict__ reg_b1,
    const float* __restrict__ reg_w2, const float* __restrict__ reg_b2,
    const float* __restrict__ reg_ln_g, const float* __restrict__ reg_ln_b,
    const float* __restrict__ out_w, const float* __restrict__ out_b,
    const float* __restrict__ ws, float* __restrict__ out)
{
    __shared__ float swgt[2*KK*HH*HH];     // w1 blocks then w2 blocks (128 KiB)
    __shared__ float gs[HH];
    const int tid = threadIdx.x;
    {   // cooperative staging: 8192 float4s over 256 threads
        const float4* g1 = reinterpret_cast<const float4*>(reg_w1);
        const float4* g2 = reinterpret_cast<const float4*>(reg_w2);
        float4* s4 = reinterpret_cast<float4*>(swgt);
        #pragma unroll
        for (int i = 0; i < 16; ++i) s4[i*256 + tid] = g1[i*256 + tid];
        #pragma unroll
        for (int i = 0; i < 16; ++i) s4[4096 + i*256 + tid] = g2[i*256 + tid];
    }
    __syncthreads();
    if (tid >= 64) return;                 // wave 0 computes; others done
    const int r = blockIdx.x;              // graph row
    const int h = tid;
    const unsigned* gk = reinterpret_cast<const unsigned*>(ws) + OFF_GKEYS;
    float g = dec_f(gk[r*HH + h]);
    for (int blk = 0; blk < 4; ++blk) {
        const float* w1 = swgt + blk*HH*HH;
        const float* w2 = swgt + KK*HH*HH + blk*HH*HH;
        gs[h] = g;
        __syncthreads();
        float t1 = reg_b1[blk*HH + h];
        #pragma unroll
        for (int hp = 0; hp < HH; ++hp) t1 += gs[hp] * w1[hp*HH + h];
        t1 = fmaxf(t1, 0.f);
        gs[h] = t1;                        // single wave: prior reads complete
        __syncthreads();
        float u = reg_b2[blk*HH + h];
        #pragma unroll
        for (int hp = 0; hp < HH; ++hp) u += gs[hp] * w2[hp*HH + h];
        __syncthreads();
        // LayerNorm over the 64 lanes
        float m = u;
        #pragma unroll
        for (int d = 1; d < 64; d <<= 1) m += __shfl_xor(m, d, 64);
        m *= (1.0f/64.0f);
        const float dv = u - m;
        float v = dv * dv;
        #pragma unroll
        for (int d = 1; d < 64; d <<= 1) v += __shfl_xor(v, d, 64);
        v *= (1.0f/64.0f);
        const float y = dv / sqrtf(v + 1e-5f) * reg_ln_g[blk*HH + h] + reg_ln_b[blk*HH + h];
        g += fmaxf(y, 0.f);
    }
    float pr = g * out_w[h];
    #pragma unroll
    for (int d = 1; d < 64; d <<= 1) pr += __shfl_xor(pr, d, 64);
    if (h == 0) out[r] = pr + out_b[0];
}

extern "C" void kernel_launch(void* const* d_in, const int* in_sizes, int n_in,
                              void* d_out, int out_size, void* d_ws, size_t ws_size,
                              hipStream_t stream)
{
    const float* adj     = (const float*)d_in[1];
    const int*   subgs   = (const int*)  d_in[2];
    const float* idemb   = (const float*)d_in[10];
    const float* id_w    = (const float*)d_in[11];
    const float* id_b    = (const float*)d_in[12];
    const float* set1_w  = (const float*)d_in[13];
    const float* set1_b  = (const float*)d_in[14];
    const float* set2_w  = (const float*)d_in[15];
    const float* set2_b  = (const float*)d_in[16];
    const float* reg_w1  = (const float*)d_in[17];
    const float* reg_b1  = (const float*)d_in[18];
    const float* reg_w2  = (const float*)d_in[19];
    const float* reg_b2  = (const float*)d_in[20];
    const float* reg_lng = (const float*)d_in[21];
    const float* reg_lnb = (const float*)d_in[22];
    const float* out_w   = (const float*)d_in[23];
    const float* out_b   = (const float*)d_in[24];
    float* ws  = (float*)d_ws;
    float* out = (float*)d_out;

    hipLaunchKernelGGL(k_tableX, dim3(NCOMBO), dim3(64),  0, stream,
                       idemb, id_w, id_b, set1_w, set1_b, ws);
    hipLaunchKernelGGL(k_main,   dim3(NSUB/2), dim3(256), 0, stream,
                       adj, subgs, set2_w, set2_b, ws);
    hipLaunchKernelGGL(k_head,   dim3(NB),     dim3(256), 0, stream,
                       reg_w1, reg_b1, reg_w2, reg_b2, reg_lng, reg_lnb,
                       out_w, out_b, ws, out);
}

// Round 9
// 140.149 us; speedup vs baseline: 2.0191x; 1.3558x over previous
//
#include <hip/hip_runtime.h>
#include <math.h>

// Static problem config
#define NB     16      // graphs
#define NN     64      // nodes per graph
#define KK     4       // subgraph size
#define PP     6       // (K-1)!
#define HH     64      // hid dim
#define NSUB   2048    // total subgraphs
#define NC0    65      // c0 in [0,64]
#define NMASK  16      // 2^K
#define NCOMBO (NC0*NMASK)
#define NVAR   5       // var = 0 (not in subg) or 1+j (i == subgs[j])

// Workspace layout (float element offsets)
#define OFF_T2     0                 // 5*1040*64         = 332800
#define OFF_GKEYS  332800            // 16*64 (as uint)   = 1024

// allperm rows: ap[j][p] for j in 0..3, p in 0..5 (values all in 0..3)
__device__ __constant__ int d_ap[4][6] = {
    {0,0,0,0,0,0},{1,1,2,2,3,3},{2,3,1,3,1,2},{3,2,3,1,2,1}};

static __device__ inline float selu_f(float x) {
    const float alpha = 1.6732632423543772f;
    const float scale = 1.0507009873554805f;
    return x > 0.0f ? scale * x : scale * alpha * expm1f(x);
}
// order-preserving float->uint encoding for atomicMax-based segment max
static __device__ inline unsigned enc_f(float x) {
    unsigned b = __float_as_uint(x);
    return (b & 0x80000000u) ? ~b : (b | 0x80000000u);
}
static __device__ inline float dec_f(unsigned k) {
    unsigned b = (k & 0x80000000u) ? (k & 0x7FFFFFFFu) : ~k;
    return __uint_as_float(b);
}

// ======= Kernel 1: T2 table, self-contained via 4-base-dot factorization ====
// labW[j][p][t] = sc_j * D[ap[j][p]][t] where D[r][t] = dot(idemb[r,:], id_w[:,t])
// and ap values are all in {0..3}: 24 dots -> 4 dots, one pass over id_w.
__global__ __launch_bounds__(64) void k_tableX(
    const float* __restrict__ idemb, const float* __restrict__ id_w,
    const float* __restrict__ id_b, const float* __restrict__ set1_w,
    const float* __restrict__ set1_b, float* __restrict__ ws)
{
    const int c = blockIdx.x;              // combo id 0..1039
    const int c0 = c >> 4, mask = c & 15;
    const int t = threadIdx.x;             // 0..63 = output channel

    if (c == 0) {                          // gk init (ready before k_main)
        unsigned* gk = reinterpret_cast<unsigned*>(ws) + OFF_GKEYS;
        for (int i = t; i < NB*HH; i += 64) gk[i] = 0u;
    }

    __shared__ float se[4][HH];            // idemb rows 0..3
    se[0][t] = idemb[0*HH + t];
    se[1][t] = idemb[1*HH + t];
    se[2][t] = idemb[2*HH + t];
    se[3][t] = idemb[3*HH + t];
    __syncthreads();

    // One pass over id_w column t: w1sum + the 4 base dots (LDS broadcast)
    float w1s = 0.f, D0 = 0.f, D1 = 0.f, D2 = 0.f, D3 = 0.f;
    #pragma unroll 8
    for (int hh = 0; hh < HH; ++hh) {
        const float wv = id_w[hh*HH + t];
        w1s += wv;
        D0 += se[0][hh] * wv;
        D1 += se[1][hh] * wv;
        D2 += se[2][hh] * wv;
        D3 += se[3][hh] * wv;
    }
    const float D[4] = {D0, D1, D2, D3};

    // acc = sum_p selu(c0*w1sum + id_b + sum_{j in mask} sc_j*D[ap[j][p]])
    const float fc0 = (float)c0;
    const float bias = id_b[t];
    float acc = 0.f;
    #pragma unroll
    for (int p = 0; p < PP; ++p) {
        float arg = fc0 * w1s + bias;
        #pragma unroll
        for (int j = 0; j < KK; ++j)
            if ((mask >> j) & 1)
                arg += ((float)(j+1) * 1000.0f) * D[d_ap[j][p]];
        acc += selu_f(arg);
    }

    // lsum[j][t] = sc_j * sum_p se[ap[j][p]][t]
    float l[KK];
    #pragma unroll
    for (int j = 0; j < KK; ++j) {
        float s = 0.f;
        #pragma unroll
        for (int p = 0; p < PP; ++p) s += se[d_ap[j][p]][t];
        l[j] = s * ((float)(j+1) * 1000.0f);
    }

    // One pass over set1_w column t: o-dot, ones-dot (cs), 4 lsum-dots
    float o = 0.f, cs = 0.f, b1 = 0.f, b2 = 0.f, b3 = 0.f, b4 = 0.f;
    #pragma unroll 8
    for (int hp = 0; hp < HH; ++hp) {
        const float s1 = set1_w[hp*HH + t];
        o  += __shfl(acc,  hp, 64) * s1;
        cs += s1;
        b1 += __shfl(l[0], hp, 64) * s1;
        b2 += __shfl(l[1], hp, 64) * s1;
        b3 += __shfl(l[2], hp, 64) * s1;
        b4 += __shfl(l[3], hp, 64) * s1;
    }
    const float s1b = set1_b[t];
    const float bw[NVAR] = { 6.0f*cs + s1b, b1 + s1b, b2 + s1b, b3 + s1b, b4 + s1b };

    #pragma unroll
    for (int var = 0; var < NVAR; ++var)
        ws[OFF_T2 + (var*NCOMBO + c)*HH + t] = selu_f(o + bw[var]);
}

// ======= Kernel 2: main pass — 2 subgraphs (same graph) per block ==========
__global__ __launch_bounds__(256) void k_main(
    const float* __restrict__ adj, const int* __restrict__ subgs,
    const float* __restrict__ set2_w, const float* __restrict__ set2_b,
    float* __restrict__ ws)
{
    const int g = blockIdx.x;             // 0..1023; 64 blocks per graph
    const int b = g >> 6;                 // graph id
    const int tid = threadIdx.x;
    const int w = tid >> 6, h = tid & 63;
    __shared__ float rs_s[NN];
    __shared__ int   sub[KK];
    __shared__ float gpart[4][HH];

    if (tid < 64) {                        // rowsum of row tid, graph b
        const float4* row = reinterpret_cast<const float4*>(adj + (b*NN + tid)*NN);
        float s = 0.f;
        #pragma unroll
        for (int k = 0; k < 16; ++k) { float4 v = row[k]; s += v.x + v.y + v.z + v.w; }
        rs_s[tid] = s;
    }
    const float* adjb = adj + b*NN*NN;
    const float* T2   = ws + OFF_T2;
    unsigned* gk = reinterpret_cast<unsigned*>(ws) + OFF_GKEYS;

    #pragma unroll
    for (int ss = 0; ss < 2; ++ss) {
        const int s = g*2 + ss;
        if (tid < KK) sub[tid] = subgs[s*KK + tid];
        __syncthreads();                   // covers rs_s (ss=0) and sub[]
        const int s0 = sub[0], s1 = sub[1], s2 = sub[2], s3 = sub[3];
        float facc = 0.f;
        #pragma unroll 4
        for (int it = 0; it < 16; ++it) {
            const int i = w*16 + it;
            const float* arow = adjb + i*NN;
            const float a0 = arow[s0], a1 = arow[s1], a2 = arow[s2], a3 = arow[s3];
            const float c0f = rs_s[i] - (a0 + a1 + a2 + a3);
            const int ic0 = (int)(c0f + 0.5f);   // exact small integer
            const int mask = (a0 != 0.f ? 1 : 0) | (a1 != 0.f ? 2 : 0)
                           | (a2 != 0.f ? 4 : 0) | (a3 != 0.f ? 8 : 0);
            const int var = (i==s0) ? 1 : (i==s1) ? 2 : (i==s2) ? 3 : (i==s3) ? 4 : 0;
            facc += T2[(var*NCOMBO + ic0*NMASK + mask)*HH + h];
        }
        gpart[w][h] = facc;
        __syncthreads();
        if (w == 0) {
            const float gsum = gpart[0][h] + gpart[1][h] + gpart[2][h] + gpart[3][h];
            float o = set2_b[h];
            #pragma unroll
            for (int hp = 0; hp < HH; ++hp)
                o += __shfl(gsum, hp, 64) * set2_w[hp*HH + h];
            const float gq = selu_f(o);
            atomicMax(gk + b*HH + h, enc_f(gq));
        }
        __syncthreads();                   // before sub[]/gpart reuse
    }
}

// ======= Kernel 3: head — one block (CU) per graph row (verified R2+) ======
__global__ __launch_bounds__(256) void k_head(
    const float* __restrict__ reg_w1, const float* __restrict__ reg_b1,
    const float* __restrict__ reg_w2, const float* __restrict__ reg_b2,
    const float* __restrict__ reg_ln_g, const float* __restrict__ reg_ln_b,
    const float* __restrict__ out_w, const float* __restrict__ out_b,
    const float* __restrict__ ws, float* __restrict__ out)
{
    __shared__ float swgt[2*KK*HH*HH];     // w1 blocks then w2 blocks (128 KiB)
    __shared__ float gs[HH];
    const int tid = threadIdx.x;
    {   // cooperative staging: 8192 float4s over 256 threads
        const float4* g1 = reinterpret_cast<const float4*>(reg_w1);
        const float4* g2 = reinterpret_cast<const float4*>(reg_w2);
        float4* s4 = reinterpret_cast<float4*>(swgt);
        #pragma unroll
        for (int i = 0; i < 16; ++i) s4[i*256 + tid] = g1[i*256 + tid];
        #pragma unroll
        for (int i = 0; i < 16; ++i) s4[4096 + i*256 + tid] = g2[i*256 + tid];
    }
    __syncthreads();
    if (tid >= 64) return;                 // wave 0 computes; others done
    const int r = blockIdx.x;              // graph row
    const int h = tid;
    const unsigned* gk = reinterpret_cast<const unsigned*>(ws) + OFF_GKEYS;
    float g = dec_f(gk[r*HH + h]);
    for (int blk = 0; blk < 4; ++blk) {
        const float* w1 = swgt + blk*HH*HH;
        const float* w2 = swgt + KK*HH*HH + blk*HH*HH;
        gs[h] = g;
        __syncthreads();
        float t1 = reg_b1[blk*HH + h];
        #pragma unroll
        for (int hp = 0; hp < HH; ++hp) t1 += gs[hp] * w1[hp*HH + h];
        t1 = fmaxf(t1, 0.f);
        gs[h] = t1;                        // single wave: prior reads complete
        __syncthreads();
        float u = reg_b2[blk*HH + h];
        #pragma unroll
        for (int hp = 0; hp < HH; ++hp) u += gs[hp] * w2[hp*HH + h];
        __syncthreads();
        // LayerNorm over the 64 lanes
        float m = u;
        #pragma unroll
        for (int d = 1; d < 64; d <<= 1) m += __shfl_xor(m, d, 64);
        m *= (1.0f/64.0f);
        const float dv = u - m;
        float v = dv * dv;
        #pragma unroll
        for (int d = 1; d < 64; d <<= 1) v += __shfl_xor(v, d, 64);
        v *= (1.0f/64.0f);
        const float y = dv / sqrtf(v + 1e-5f) * reg_ln_g[blk*HH + h] + reg_ln_b[blk*HH + h];
        g += fmaxf(y, 0.f);
    }
    float pr = g * out_w[h];
    #pragma unroll
    for (int d = 1; d < 64; d <<= 1) pr += __shfl_xor(pr, d, 64);
    if (h == 0) out[r] = pr + out_b[0];
}

extern "C" void kernel_launch(void* const* d_in, const int* in_sizes, int n_in,
                              void* d_out, int out_size, void* d_ws, size_t ws_size,
                              hipStream_t stream)
{
    const float* adj     = (const float*)d_in[1];
    const int*   subgs   = (const int*)  d_in[2];
    const float* idemb   = (const float*)d_in[10];
    const float* id_w    = (const float*)d_in[11];
    const float* id_b    = (const float*)d_in[12];
    const float* set1_w  = (const float*)d_in[13];
    const float* set1_b  = (const float*)d_in[14];
    const float* set2_w  = (const float*)d_in[15];
    const float* set2_b  = (const float*)d_in[16];
    const float* reg_w1  = (const float*)d_in[17];
    const float* reg_b1  = (const float*)d_in[18];
    const float* reg_w2  = (const float*)d_in[19];
    const float* reg_b2  = (const float*)d_in[20];
    const float* reg_lng = (const float*)d_in[21];
    const float* reg_lnb = (const float*)d_in[22];
    const float* out_w   = (const float*)d_in[23];
    const float* out_b   = (const float*)d_in[24];
    float* ws  = (float*)d_ws;
    float* out = (float*)d_out;

    hipLaunchKernelGGL(k_tableX, dim3(NCOMBO), dim3(64),  0, stream,
                       idemb, id_w, id_b, set1_w, set1_b, ws);
    hipLaunchKernelGGL(k_main,   dim3(NSUB/2), dim3(256), 0, stream,
                       adj, subgs, set2_w, set2_b, ws);
    hipLaunchKernelGGL(k_head,   dim3(NB),     dim3(256), 0, stream,
                       reg_w1, reg_b1, reg_w2, reg_b2, reg_lng, reg_lnb,
                       out_w, out_b, ws, out);
}